// Round 5
// baseline (914.024 us; speedup 1.0000x reference)
//
#include <hip/hip_runtime.h>
#include <stdint.h>

typedef __bf16 bf16_t;
typedef __bf16 bf16x8 __attribute__((ext_vector_type(8)));
typedef __bf16 bf16x4 __attribute__((ext_vector_type(4)));
typedef float f32x4 __attribute__((ext_vector_type(4)));
typedef float f32x2 __attribute__((ext_vector_type(2)));

#define LOG2E 1.4426950408889634f

__device__ __forceinline__ float relu_(float v) { return v > 0.f ? v : 0.f; }

// ---------------------------------------------------------------- prep
// params layout (floats):
// 0 bn1_scale[128] |128 bn1_shift[128] |256 bn2_scale[16] |272 bn2_shift[16]
// 288 sa_scale[64] |352 sa_shift[64] |416 fuse_scale[128] |544 fuse_shift[128]
// 672 bns1_scale[512] |1184 bns1_shift[512] |1696 bns2_scale[256] |1952 bns2_shift[256]
__global__ __launch_bounds__(256) void k_prep(
    const float* __restrict__ convs1_w, const float* __restrict__ convs2_w,
    const float* __restrict__ bn1, const float* __restrict__ bn2,
    const float* __restrict__ sa_bn, const float* __restrict__ sa_trans_b,
    const float* __restrict__ fuse_bn, const float* __restrict__ convs1_b,
    const float* __restrict__ bns1, const float* __restrict__ convs2_b,
    const float* __restrict__ bns2,
    bf16_t* __restrict__ wbuf1, bf16_t* __restrict__ wbuf2, float* __restrict__ params,
    float* __restrict__ Lbuf)
{
  int idx = blockIdx.x * 256 + threadIdx.x;
  // zero per-layer softmax row-sum accumulators L[4][16][2048]
  Lbuf[idx] = 0.f;
  Lbuf[idx + 65536] = 0.f;
  for (int it = 0; it < 3; ++it) {
    int i = idx + it * 65536;
    if (i < 65536) {                        // wbuf1 [512][128] = first 128 cols of convs1_w
      int o = i >> 7, c = i & 127;
      wbuf1[i] = (bf16_t)convs1_w[o * 264 + c];
    } else if (i < 65536 + 131072) {        // wbuf2 [256][512]
      int j = i - 65536;
      wbuf2[j] = (bf16_t)convs2_w[j];
    }
  }
  if (blockIdx.x == 0) {
    for (int t = threadIdx.x; t < 1104; t += 256) {
      float g, be, m, v, extra = 0.f; int so, ho;
      if (t < 128)      { g=bn1[t]; be=bn1[128+t]; m=bn1[256+t]; v=bn1[384+t]; so=t; ho=128+t; }
      else if (t < 144) { int u=t-128; g=bn2[u]; be=bn2[16+u]; m=bn2[32+u]; v=bn2[48+u]; so=256+u; ho=272+u; }
      else if (t < 208) { int u=t-144; int L=u>>4, o=u&15; const float* p=sa_bn+L*64;
                          g=p[o]; be=p[16+o]; m=p[32+o]; v=p[48+o];
                          extra=sa_trans_b[L*16+o]; so=288+u; ho=352+u; }
      else if (t < 336) { int u=t-208; g=fuse_bn[u]; be=fuse_bn[128+u]; m=fuse_bn[256+u]; v=fuse_bn[384+u]; so=416+u; ho=544+u; }
      else if (t < 848) { int u=t-336; g=bns1[u]; be=bns1[512+u]; m=bns1[1024+u]; v=bns1[1536+u]; extra=convs1_b[u]; so=672+u; ho=1184+u; }
      else              { int u=t-848; g=bns2[u]; be=bns2[256+u]; m=bns2[512+u]; v=bns2[768+u]; extra=convs2_b[u]; so=1696+u; ho=1952+u; }
      float sc = g * rsqrtf(v + 1e-5f);
      params[so] = sc;
      params[ho] = (extra - m) * sc + be;
    }
  }
}

// ---------------------------------------------------------------- fused conv1(16->128)+bn+relu -> conv2(128->16)+bn+relu -> layer0 k/v
__global__ __launch_bounds__(256) void k_convs(const float* __restrict__ x,
    const float* __restrict__ w1, const float* __restrict__ w2,
    const float* __restrict__ params, const float* __restrict__ qk_w,
    const float* __restrict__ v_w, const float* __restrict__ v_b,
    float* __restrict__ h0, float* __restrict__ kbuf, float* __restrict__ vbufT)
{
  __shared__ float xs[16 * 64];
  __shared__ float ws1[128 * 17];
  __shared__ float ws2[16 * 129];
  __shared__ __align__(16) float h1s[128 * 64];
  __shared__ float hcv[64 * 17];
  __shared__ float qk[64], vw[256], vb[16], sc1[128], sh1[128], sc2[16], sh2[16];
  int t = threadIdx.x;
  int bid = blockIdx.x;                       // 512 = b*32 + chunk(64 cols)
  int b = bid >> 5, n0 = (bid & 31) * 64;
  for (int i = t; i < 1024; i += 256) { int c = i >> 6, col = i & 63; xs[i] = x[((size_t)b * 16 + c) * 2048 + n0 + col]; }
  for (int i = t; i < 2048; i += 256) { int o = i >> 4, c = i & 15;  ws1[o * 17 + c]  = w1[i]; }
  for (int i = t; i < 2048; i += 256) { int o = i >> 7, c = i & 127; ws2[o * 129 + c] = w2[i]; }
  if (t < 64) qk[t] = qk_w[t];
  vw[t] = v_w[t];
  if (t < 16) { vb[t] = v_b[t]; sc2[t] = params[256 + t]; sh2[t] = params[272 + t]; }
  if (t < 128) { sc1[t] = params[t]; sh1[t] = params[128 + t]; }
  __syncthreads();
  int col = t & 63, og = t >> 6;
  float xr[16];
#pragma unroll
  for (int c = 0; c < 16; ++c) xr[c] = xs[c * 64 + col];
#pragma unroll 4
  for (int i = 0; i < 32; ++i) {
    int o = og * 32 + i;
    float s = 0.f;
#pragma unroll
    for (int c = 0; c < 16; ++c) s = fmaf(ws1[o * 17 + c], xr[c], s);
    h1s[o * 64 + col] = relu_(fmaf(s, sc1[o], sh1[o]));
  }
  __syncthreads();
  float a[4] = {0.f, 0.f, 0.f, 0.f};
  for (int c = 0; c < 128; ++c) {
    float hv = h1s[c * 64 + col];
#pragma unroll
    for (int oo = 0; oo < 4; ++oo) a[oo] = fmaf(ws2[(og * 4 + oo) * 129 + c], hv, a[oo]);
  }
#pragma unroll
  for (int oo = 0; oo < 4; ++oo) {
    int o = og * 4 + oo;
    float v = relu_(fmaf(a[oo], sc2[o], sh2[o]));
    h0[((size_t)b * 16 + o) * 2048 + n0 + col] = v;
    hcv[col * 17 + o] = v;
  }
  __syncthreads();
  float hr[16];
#pragma unroll
  for (int c = 0; c < 16; ++c) hr[c] = hcv[col * 17 + c];
#pragma unroll
  for (int i = 0; i < 5; ++i) {
    int u = og * 5 + i;
    const float* W = (u < 4) ? &qk[u * 16] : &vw[(u - 4) * 16];
    float s = (u < 4) ? 0.f : vb[u - 4];
#pragma unroll
    for (int c = 0; c < 16; ++c) s = fmaf(W[c], hr[c], s);
    if (u < 4) kbuf[((size_t)b * 2048 + n0 + col) * 4 + u] = s;
    else       vbufT[((size_t)b * 2048 + n0 + col) * 16 + (u - 4)] = s;
  }
}

// ---------------------------------------------------------------- pass A: row softmax denominators (16 m-splits, atomic combine)
__global__ __launch_bounds__(256) void k_rowstats(const float* __restrict__ kbuf, float* __restrict__ Lb)
{
  __shared__ float4 kch[128];
  int bid = blockIdx.x;                     // 2048 = b*128 + nt*16 + ms
  int b = bid >> 7, nt = (bid >> 4) & 7, ms = bid & 15;
  int t = threadIdx.x;
  const float4* kb = (const float4*)kbuf + b * 2048;
  if (t < 128) kch[t] = kb[ms * 128 + t];
  __syncthreads();
  int n = nt * 256 + t;
  float4 q = kb[n];
  q.x *= LOG2E; q.y *= LOG2E; q.z *= LOG2E; q.w *= LOG2E;
  float L = 0.f;
#pragma unroll 4
  for (int m = 0; m < 128; ++m) {
    float4 k4 = kch[m];
    float s = fmaf(q.x, k4.x, fmaf(q.y, k4.y, fmaf(q.z, k4.z, q.w * k4.w)));
    L += exp2f(s);
  }
  atomicAdd(&Lb[b * 2048 + n], L);
}

// ---------------------------------------------------------------- pass B: E-matrix + split-bf16 MFMA PV (16 n-splits)
// E[n,m] = exp2(log2e*(k_n.k_m) - log2 L_n); x_r_part[c,m] = sum_n V[c,n]*E[n,m]
__global__ __launch_bounds__(256, 4) void k_attn(const float* __restrict__ kbuf,
    const float* __restrict__ vbufT, const float* __restrict__ Lb, float* __restrict__ parts)
{
  __shared__ float skn[128 * 8];            // [n][0..3]=k4, [4]=-log2(L)
  __shared__ __align__(16) float4 skm[512];
  int t = threadIdx.x;
  int bid = blockIdx.x;                     // 1024 = b*64 + ns*4 + mq
  int b = bid >> 6, ns = (bid >> 2) & 15, mq = bid & 3;
  if (t < 128) {
    int n = ns * 128 + t;
    float4 k4 = ((const float4*)kbuf)[b * 2048 + n];
    *(float4*)&skn[t * 8] = k4;
    skn[t * 8 + 4] = -__log2f(Lb[b * 2048 + n]);
  }
  skm[t]       = ((const float4*)kbuf)[b * 2048 + mq * 512 + t];
  skm[t + 256] = ((const float4*)kbuf)[b * 2048 + mq * 512 + t + 256];
  __syncthreads();
  int lane = t & 63, w = t >> 6;
  int lg16 = lane >> 4, c = lane & 15;
  // register-resident V fragments (A-side), exact split v = hi + lo
  bf16x8 vhi[4], vlo[4];
#pragma unroll
  for (int s = 0; s < 4; ++s) {
#pragma unroll
    for (int j = 0; j < 8; ++j) {
      int n = ns * 128 + s * 32 + lg16 * 8 + j;
      float v = vbufT[((size_t)b * 2048 + n) * 16 + c];
      bf16_t h = (bf16_t)v;
      vhi[s][j] = h;
      vlo[s][j] = (bf16_t)(v - (float)h);
    }
  }
  bf16x8 ones;
#pragma unroll
  for (int j = 0; j < 8; ++j) ones[j] = (bf16_t)1.0f;

  float* pb = parts + ((size_t)(ns * 16 + b) * 17) * 2048;
  for (int it = 0; it < 8; ++it) {
    int tm = w * 8 + it;                    // m-tile index within 512-m range
    int mb = mq * 512 + tm * 16;
    float4 km = skm[tm * 16 + c];
    km.x *= LOG2E; km.y *= LOG2E; km.z *= LOG2E; km.w *= LOG2E;
    f32x4 acc = {0.f, 0.f, 0.f, 0.f};
    f32x4 acc2 = {0.f, 0.f, 0.f, 0.f};
#pragma unroll
    for (int s = 0; s < 4; ++s) {
      float e[8];
#pragma unroll
      for (int j = 0; j < 8; ++j) {
        const float* kp = &skn[(s * 32 + lg16 * 8 + j) * 8];
        float sc = fmaf(km.x, kp[0], fmaf(km.y, kp[1], fmaf(km.z, kp[2], fmaf(km.w, kp[3], kp[4]))));
        e[j] = exp2f(sc);
      }
      bf16x8 eh, el;
#pragma unroll
      for (int j = 0; j < 8; ++j) {
        bf16_t h = (bf16_t)e[j];
        eh[j] = h;
        el[j] = (bf16_t)(e[j] - (float)h);
      }
      acc  = __builtin_amdgcn_mfma_f32_16x16x32_bf16(vhi[s], eh, acc, 0, 0, 0);
      acc  = __builtin_amdgcn_mfma_f32_16x16x32_bf16(vlo[s], eh, acc, 0, 0, 0);
      acc  = __builtin_amdgcn_mfma_f32_16x16x32_bf16(vhi[s], el, acc, 0, 0, 0);
      acc2 = __builtin_amdgcn_mfma_f32_16x16x32_bf16(ones,  eh, acc2, 0, 0, 0);
      acc2 = __builtin_amdgcn_mfma_f32_16x16x32_bf16(ones,  el, acc2, 0, 0, 0);
    }
    float* pp = pb + mb + c;
#pragma unroll
    for (int r = 0; r < 4; ++r)
      pp[(size_t)(lg16 * 4 + r) * 2048] = acc[r];
    if (lane < 16) pp[(size_t)16 * 2048] = acc2[0];
  }
}

// ---------------------------------------------------------------- SA epilogue: combine + trans/bn/relu + residual (+ next k/v)
__global__ __launch_bounds__(256) void k_epilogue(const float* __restrict__ parts,
    const float* __restrict__ hin, int hbs, const float* __restrict__ t_w,
    const float* __restrict__ params, int layer, float* __restrict__ hout,
    const float* __restrict__ qk_w, const float* __restrict__ v_w, const float* __restrict__ v_b,
    float* __restrict__ kbuf, float* __restrict__ vbufT)
{
  __shared__ __align__(16) float pd[17 * 64];
  __shared__ float hs[16 * 64];
  __shared__ float dl[16 * 64];
  __shared__ float hv[64 * 17];
  __shared__ float tw[256], qk[64], vw[256], vb[16], sc[16], sh[16];
  int t = threadIdx.x;
  int bid = blockIdx.x;                     // 512 = b*32 + chunk(64 cols)
  int b = bid >> 5, n0 = (bid & 31) * 64;
  tw[t] = t_w[t];
  if (qk_w) { if (t < 64) qk[t] = qk_w[t]; vw[t] = v_w[t]; if (t < 16) vb[t] = v_b[t]; }
  if (t < 16) { sc[t] = params[288 + layer * 16 + t]; sh[t] = params[352 + layer * 16 + t]; }
  for (int i = t; i < 272; i += 256) {
    int r = i >> 4, c4 = (i & 15) << 2;
    f32x4 s = {0.f, 0.f, 0.f, 0.f};
#pragma unroll
    for (int sp = 0; sp < 16; ++sp)
      s += *(const f32x4*)&parts[((size_t)(sp * 16 + b) * 17 + r) * 2048 + n0 + c4];
    *(f32x4*)&pd[r * 64 + c4] = s;
  }
  for (int i = t; i < 1024; i += 256) {
    int c = i >> 6, col = i & 63;
    hs[i] = hin[(size_t)b * hbs + (size_t)c * 2048 + n0 + col];
  }
  __syncthreads();
  int col = t & 63, g4 = t >> 6;
  float inv = 1.f / (1e-9f + pd[16 * 64 + col]);
#pragma unroll
  for (int j = 0; j < 4; ++j) {
    int c = g4 * 4 + j;
    dl[c * 64 + col] = hs[c * 64 + col] - pd[c * 64 + col] * inv;
  }
  __syncthreads();
#pragma unroll
  for (int j = 0; j < 4; ++j) {
    int o = g4 * 4 + j;
    float y = 0.f;
#pragma unroll
    for (int c = 0; c < 16; ++c) y = fmaf(tw[o * 16 + c], dl[c * 64 + col], y);
    y = relu_(fmaf(y, sc[o], sh[o]));
    float hh = hs[o * 64 + col] + y;
    hout[(size_t)b * 64 * 2048 + (size_t)o * 2048 + n0 + col] = hh;
    hv[col * 17 + o] = hh;
  }
  if (qk_w) {
    __syncthreads();
    float hr[16];
#pragma unroll
    for (int c = 0; c < 16; ++c) hr[c] = hv[col * 17 + c];
#pragma unroll
    for (int i = 0; i < 5; ++i) {
      int u = g4 * 5 + i;
      const float* W = (u < 4) ? &qk[u * 16] : &vw[(u - 4) * 16];
      float s = (u < 4) ? 0.f : vb[u - 4];
#pragma unroll
      for (int c = 0; c < 16; ++c) s = fmaf(W[c], hr[c], s);
      if (u < 4) kbuf[((size_t)b * 2048 + n0 + col) * 4 + u] = s;
      else       vbufT[((size_t)b * 2048 + n0 + col) * 16 + (u - 4)] = s;
    }
  }
}

// ---------------------------------------------------------------- fuse conv (64->128) + bn + leaky relu
__global__ __launch_bounds__(256) void k_fuse(const float* __restrict__ feats, const float* __restrict__ fw,
    const float* __restrict__ params, float* __restrict__ xqqw, bf16_t* __restrict__ gbuf)
{
  __shared__ float ws[128 * 65];
  __shared__ __align__(16) float fst[64 * 64];
  __shared__ float sc[128], sh[128];
  int t = threadIdx.x, bid = blockIdx.x;    // 512 = b*32 + chunk(64 cols)
  int b = bid >> 5, n0 = (bid & 31) * 64;
  for (int i = t; i < 8192; i += 256) { int o = i >> 6, c = i & 63; ws[o * 65 + c] = fw[i]; }
  for (int i = t; i < 4096; i += 256) { int c = i >> 6, col = i & 63; fst[i] = feats[((size_t)b * 64 + c) * 2048 + n0 + col]; }
  if (t < 128) { sc[t] = params[416 + t]; sh[t] = params[544 + t]; }
  __syncthreads();
  int cg = t & 7, og = t >> 3;
  f32x2 acc[4][4];
#pragma unroll
  for (int oo = 0; oo < 4; ++oo)
#pragma unroll
    for (int j = 0; j < 4; ++j) acc[oo][j] = (f32x2){0.f, 0.f};
  for (int c = 0; c < 64; ++c) {
    const f32x2* fp = (const f32x2*)&fst[c * 64 + cg * 8];
    f32x2 f0 = fp[0], f1 = fp[1], f2v = fp[2], f3 = fp[3];
#pragma unroll
    for (int oo = 0; oo < 4; ++oo) {
      float w = ws[(og * 4 + oo) * 65 + c];
      f32x2 wv = {w, w};
      acc[oo][0] += wv * f0; acc[oo][1] += wv * f1;
      acc[oo][2] += wv * f2v; acc[oo][3] += wv * f3;
    }
  }
  float y[4][8];
#pragma unroll
  for (int oo = 0; oo < 4; ++oo) {
    int o = og * 4 + oo;
    float s0 = sc[o], s1 = sh[o];
#pragma unroll
    for (int j = 0; j < 8; ++j) {
      float v = fmaf(acc[oo][j >> 1][j & 1], s0, s1);
      y[oo][j] = v > 0.f ? v : 0.2f * v;
    }
    float4 v0 = {y[oo][0], y[oo][1], y[oo][2], y[oo][3]};
    float4 v1 = {y[oo][4], y[oo][5], y[oo][6], y[oo][7]};
    *(float4*)&xqqw[((size_t)b * 128 + o) * 2048 + n0 + cg * 8] = v0;
    *(float4*)&xqqw[((size_t)b * 128 + o) * 2048 + n0 + cg * 8 + 4] = v1;
  }
#pragma unroll
  for (int j = 0; j < 8; ++j) {
    int col = n0 + cg * 8 + j;
    bf16x4 pk;
    pk[0] = (bf16_t)y[0][j]; pk[1] = (bf16_t)y[1][j];
    pk[2] = (bf16_t)y[2][j]; pk[3] = (bf16_t)y[3][j];
    *(bf16x4*)&gbuf[((size_t)b * 2048 + col) * 128 + og * 4] = pk;
  }
}

// ---------------------------------------------------------------- argmax over n (+ batch-1 channel means)
__global__ __launch_bounds__(256) void k_argmax(const float* __restrict__ xqqw,
    float* __restrict__ xmaxf, float* __restrict__ xavg)
{
  __shared__ float sv[256]; __shared__ int si[256]; __shared__ float ss[256];
  int bo = blockIdx.x;                     // b*128+o
  int b = bo >> 7, o = bo & 127;
  const float* row = xqqw + (size_t)bo * 2048;
  int tid = threadIdx.x;
  float best = -3.4e38f; int bi = 0; float sum = 0.f;
#pragma unroll
  for (int j = 0; j < 8; ++j) {
    int n = j * 256 + tid;
    float v = row[n];
    sum += v;
    if (v > best) { best = v; bi = n; }
  }
  sv[tid] = best; si[tid] = bi; ss[tid] = sum;
  __syncthreads();
  for (int s = 128; s > 0; s >>= 1) {
    if (tid < s) {
      float v2 = sv[tid + s]; int i2 = si[tid + s];
      if (v2 > sv[tid] || (v2 == sv[tid] && i2 < si[tid])) { sv[tid] = v2; si[tid] = i2; }
      ss[tid] += ss[tid + s];
    }
    __syncthreads();
  }
  if (tid == 0) {
    xmaxf[bo] = (float)si[0];
    if (b == 1) xavg[o] = ss[0] * (1.0f / 2048.0f);
  }
}

// ---------------------------------------------------------------- exact fp32 bias from x_max/x_avg rows (replaces g rows 128..287)
__global__ __launch_bounds__(256) void k_bias2(const float* __restrict__ w1,
    const float* __restrict__ xmaxf, const float* __restrict__ xavg,
    const float* __restrict__ params, float* __restrict__ bias2)
{
  int id = blockIdx.x * 256 + threadIdx.x;   // 8192 = o*16 + b
  int o = id >> 4, b = id & 15;
  const float* wr = w1 + (size_t)o * 264;
  float s = 0.f;
  for (int u = 0; u < 128; ++u) s = fmaf(wr[128 + u], xmaxf[b * 128 + u], s);
#pragma unroll
  for (int u = 0; u < 8; ++u)  s = fmaf(wr[256 + u], xavg[b * 8 + u], s);
  bias2[b * 512 + o] = s * params[672 + o];
}

// ---------------------------------------------------------------- bf16 MFMA GEMM: Cout[bn][o] = relu(bn(A[o][:].B[bn][:]) + bias2)
__global__ __launch_bounds__(256) void k_gemm(const bf16_t* __restrict__ A, const bf16_t* __restrict__ Bm,
    const float* __restrict__ scp, const float* __restrict__ shp, const float* __restrict__ bias2,
    bf16_t* __restrict__ Cout, int M, int K, int mtiles)
{
  __shared__ bf16_t At[128 * 32];
  __shared__ bf16_t Bt[128 * 32];
  int tid = threadIdx.x;
  int mt = blockIdx.x % mtiles, ct = blockIdx.x / mtiles;
  int srow = tid >> 2, scol = (tid & 3) << 3;
  const bf16_t* ga = A  + (size_t)(mt * 128 + srow) * K + scol;
  const bf16_t* gb = Bm + (size_t)(ct * 128 + srow) * K + scol;
  int lane = tid & 63, wave = tid >> 6;
  int wr = (wave >> 1) * 64, wc = (wave & 1) * 64;
  int frow = lane & 15, fk = (lane >> 4) * 8;
  const f32x4 z4 = {0.f, 0.f, 0.f, 0.f};
  f32x4 acc[4][4];
#pragma unroll
  for (int i = 0; i < 4; ++i)
#pragma unroll
    for (int j = 0; j < 4; ++j) acc[i][j] = z4;
  uint4 ra0 = *(const uint4*)ga, ra1 = *(const uint4*)(ga + (size_t)64 * K);
  uint4 rb0 = *(const uint4*)gb, rb1 = *(const uint4*)(gb + (size_t)64 * K);
  int ksteps = K >> 5;
  for (int ks = 0; ks < ksteps; ++ks) {
    __syncthreads();
    *(uint4*)&At[tid * 8] = ra0;  *(uint4*)&At[2048 + tid * 8] = ra1;
    *(uint4*)&Bt[tid * 8] = rb0;  *(uint4*)&Bt[2048 + tid * 8] = rb1;
    __syncthreads();
    if (ks + 1 < ksteps) {
      ra0 = *(const uint4*)(ga + (ks + 1) * 32);
      ra1 = *(const uint4*)(ga + (size_t)64 * K + (ks + 1) * 32);
      rb0 = *(const uint4*)(gb + (ks + 1) * 32);
      rb1 = *(const uint4*)(gb + (size_t)64 * K + (ks + 1) * 32);
    }
    bf16x8 af[4], bfr[4];
#pragma unroll
    for (int i = 0; i < 4; ++i) af[i]  = *(const bf16x8*)&At[(wr + i * 16 + frow) * 32 + fk];
#pragma unroll
    for (int j = 0; j < 4; ++j) bfr[j] = *(const bf16x8*)&Bt[(wc + j * 16 + frow) * 32 + fk];
#pragma unroll
    for (int i = 0; i < 4; ++i)
#pragma unroll
      for (int j = 0; j < 4; ++j)
        acc[i][j] = __builtin_amdgcn_mfma_f32_16x16x32_bf16(af[i], bfr[j], acc[i][j], 0, 0, 0);
  }
  int crow = (lane >> 4) * 4, ccol = lane & 15;
#pragma unroll
  for (int i = 0; i < 4; ++i) {
    int o0 = mt * 128 + wr + i * 16 + crow;
    float s0 = scp[o0], s1 = scp[o0+1], s2 = scp[o0+2], s3 = scp[o0+3];
    float t0 = shp[o0], t1 = shp[o0+1], t2 = shp[o0+2], t3 = shp[o0+3];
#pragma unroll
    for (int j = 0; j < 4; ++j) {
      int bn = ct * 128 + wc + j * 16 + ccol;
      float b0 = 0.f, b1 = 0.f, b2 = 0.f, b3 = 0.f;
      if (bias2) {
        const float* bp = bias2 + (size_t)(bn >> 11) * M + o0;
        b0 = bp[0]; b1 = bp[1]; b2 = bp[2]; b3 = bp[3];
      }
      bf16x4 pk;
      pk[0] = (bf16_t)relu_(fmaf(acc[i][j][0], s0, t0 + b0));
      pk[1] = (bf16_t)relu_(fmaf(acc[i][j][1], s1, t1 + b1));
      pk[2] = (bf16_t)relu_(fmaf(acc[i][j][2], s2, t2 + b2));
      pk[3] = (bf16_t)relu_(fmaf(acc[i][j][3], s3, t3 + b3));
      *(bf16x4*)(Cout + (size_t)bn * M + o0) = pk;
    }
  }
}

// ---------------------------------------------------------------- convs3 (256->16) + bias, fp32 out
__global__ __launch_bounds__(256) void k_gemm3(const bf16_t* __restrict__ g2, const float* __restrict__ w3,
    const float* __restrict__ b3, float* __restrict__ out)
{
  __shared__ float wsT[4096];   // [k][o]
  __shared__ float bb[16];
  int t = threadIdx.x;
  for (int i = t; i < 4096; i += 256) { int o = i >> 8, k = i & 255; wsT[k * 16 + o] = w3[i]; }
  if (t < 16) bb[t] = b3[t];
  __syncthreads();
  int col = blockIdx.x * 64 + (t & 63);     // grid 512
  int og = t >> 6;
  int b = col >> 11, n = col & 2047;
  const bf16_t* g = g2 + (size_t)col * 256;
  float acc[4] = {0.f, 0.f, 0.f, 0.f};
  for (int k0 = 0; k0 < 256; k0 += 8) {
    bf16x8 gv8 = *(const bf16x8*)(g + k0);
#pragma unroll
    for (int kk = 0; kk < 8; ++kk) {
      float gv = (float)gv8[kk];
      const float* wr = &wsT[(k0 + kk) * 16 + og * 4];
#pragma unroll
      for (int oo = 0; oo < 4; ++oo) acc[oo] = fmaf(wr[oo], gv, acc[oo]);
    }
  }
  float* op = out + (size_t)b * 16 * 2048 + n;
#pragma unroll
  for (int oo = 0; oo < 4; ++oo) {
    int o = og * 4 + oo;
    op[(size_t)o * 2048] = acc[oo] + bb[o];
  }
}

// ---------------------------------------------------------------- launch
extern "C" void kernel_launch(void* const* d_in, const int* in_sizes, int n_in,
                              void* d_out, int out_size, void* d_ws, size_t ws_size,
                              hipStream_t stream)
{
  const float* x         = (const float*)d_in[0];
  const float* conv1_w   = (const float*)d_in[1];
  const float* bn1       = (const float*)d_in[2];
  const float* conv2_w   = (const float*)d_in[3];
  const float* bn2       = (const float*)d_in[4];
  const float* sa_qk_w   = (const float*)d_in[5];
  const float* sa_v_w    = (const float*)d_in[6];
  const float* sa_v_b    = (const float*)d_in[7];
  const float* sa_trans_w= (const float*)d_in[8];
  const float* sa_trans_b= (const float*)d_in[9];
  const float* sa_bn     = (const float*)d_in[10];
  const float* fuse_w    = (const float*)d_in[11];
  const float* fuse_bn   = (const float*)d_in[12];
  const float* convs1_w  = (const float*)d_in[13];
  const float* convs1_b  = (const float*)d_in[14];
  const float* bns1      = (const float*)d_in[15];
  const float* convs2_w  = (const float*)d_in[16];
  const float* convs2_b  = (const float*)d_in[17];
  const float* bns2      = (const float*)d_in[18];
  const float* convs3_w  = (const float*)d_in[19];
  const float* convs3_b  = (const float*)d_in[20];

  char* ws = (char*)d_ws;
  float*  xqqw  = (float*)(ws + 0);            // 16 MB
  float*  feats = (float*)(ws + 16777216);     // 8 MB
  float*  h0    = (float*)(ws + 25165824);     // 2 MB
  float*  kbuf  = (float*)(ws + 27262976);     // 0.5 MB
  float*  vbufT = (float*)(ws + 27787264);     // 2 MB
  float*  Lbuf  = (float*)(ws + 29884416);     // 512 KB  [4][16][2048]
  float*  parts = (float*)(ws + 31981568);     // 35.65 MB  [16][16][17][2048] f32
  bf16_t* g1    = (bf16_t*)(ws + 0);           // 32 MB, overlays xqqw/feats/h0/attn (dead)
  bf16_t* g2    = (bf16_t*)(ws + 33554432);    // 16 MB, overlays parts (dead)
  bf16_t* gbuf  = (bf16_t*)(ws + 50331648);    // 8 MB, overlays parts tail (dead)
  bf16_t* wbuf1 = (bf16_t*)(ws + 67633152);    // 128 KB
  bf16_t* wbuf2 = (bf16_t*)(ws + 67764224);    // 256 KB
  float*  params= (float*)(ws + 68026368);
  float*  xmaxf = (float*)(ws + 68042752);
  float*  xavg  = (float*)(ws + 68050944);
  float*  bias2 = (float*)(ws + 68055040);

  k_prep<<<256, 256, 0, stream>>>(convs1_w, convs2_w, bn1, bn2, sa_bn, sa_trans_b, fuse_bn,
                                  convs1_b, bns1, convs2_b, bns2, wbuf1, wbuf2, params, Lbuf);
  k_convs<<<512, 256, 0, stream>>>(x, conv1_w, conv2_w, params, sa_qk_w, sa_v_w, sa_v_b,
                                   h0, kbuf, vbufT);
  for (int i = 0; i < 4; ++i) {
    float* Lb = Lbuf + (size_t)i * 32768;
    k_rowstats<<<2048, 256, 0, stream>>>(kbuf, Lb);
    k_attn<<<1024, 256, 0, stream>>>(kbuf, vbufT, Lb, parts);
    const float* hin = (i == 0) ? h0 : (feats + (size_t)(i - 1) * 16 * 2048);
    int hbs = (i == 0) ? 16 * 2048 : 64 * 2048;
    bool last = (i == 3);
    k_epilogue<<<512, 256, 0, stream>>>(parts, hin, hbs, sa_trans_w + i * 256, params, i,
        feats + (size_t)i * 16 * 2048,
        last ? nullptr : sa_qk_w + (i + 1) * 64,
        last ? nullptr : sa_v_w + (i + 1) * 256,
        last ? nullptr : sa_v_b + (i + 1) * 16,
        kbuf, vbufT);
  }
  k_fuse<<<512, 256, 0, stream>>>(feats, fuse_w, params, xqqw, gbuf);
  k_argmax<<<2048, 256, 0, stream>>>(xqqw, xmaxf, xavg);
  k_bias2<<<32, 256, 0, stream>>>(convs1_w, xmaxf, xavg, params, bias2);
  k_gemm<<<1024, 256, 0, stream>>>(wbuf1, gbuf, params + 672, params + 1184, bias2, g1, 512, 128, 4);
  k_gemm<<<512, 256, 0, stream>>>(wbuf2, g1, params + 1696, params + 1952, nullptr, g2, 256, 512, 2);
  k_gemm3<<<512, 256, 0, stream>>>(g2, convs3_w, convs3_b, (float*)d_out);
}

// Round 7
// 496.599 us; speedup vs baseline: 1.8406x; 1.8406x over previous
//
#include <hip/hip_runtime.h>
#include <stdint.h>

typedef __bf16 bf16_t;
typedef __bf16 bf16x8 __attribute__((ext_vector_type(8)));
typedef __bf16 bf16x4 __attribute__((ext_vector_type(4)));
typedef float f32x4 __attribute__((ext_vector_type(4)));
typedef float f32x2 __attribute__((ext_vector_type(2)));

#define LOG2E 1.4426950408889634f

__device__ __forceinline__ float relu_(float v) { return v > 0.f ? v : 0.f; }

// ---------------------------------------------------------------- prep
// params layout (floats):
// 0 bn1_scale[128] |128 bn1_shift[128] |256 bn2_scale[16] |272 bn2_shift[16]
// 288 sa_scale[64] |352 sa_shift[64] |416 fuse_scale[128] |544 fuse_shift[128]
// 672 bns1_scale[512] |1184 bns1_shift[512] |1696 bns2_scale[256] |1952 bns2_shift[256]
__global__ __launch_bounds__(256) void k_prep(
    const float* __restrict__ convs1_w, const float* __restrict__ convs2_w,
    const float* __restrict__ bn1, const float* __restrict__ bn2,
    const float* __restrict__ sa_bn, const float* __restrict__ sa_trans_b,
    const float* __restrict__ fuse_bn, const float* __restrict__ convs1_b,
    const float* __restrict__ bns1, const float* __restrict__ convs2_b,
    const float* __restrict__ bns2,
    bf16_t* __restrict__ wbuf1, bf16_t* __restrict__ wbuf2, float* __restrict__ params,
    float* __restrict__ Lbuf)
{
  int idx = blockIdx.x * 256 + threadIdx.x;
  // zero per-layer softmax row-sum accumulators L[4][16][2048]
  Lbuf[idx] = 0.f;
  Lbuf[idx + 65536] = 0.f;
  for (int it = 0; it < 3; ++it) {
    int i = idx + it * 65536;
    if (i < 65536) {                        // wbuf1 [512][128] = first 128 cols of convs1_w
      int o = i >> 7, c = i & 127;
      wbuf1[i] = (bf16_t)convs1_w[o * 264 + c];
    } else if (i < 65536 + 131072) {        // wbuf2 [256][512]
      int j = i - 65536;
      wbuf2[j] = (bf16_t)convs2_w[j];
    }
  }
  if (blockIdx.x == 0) {
    for (int t = threadIdx.x; t < 1104; t += 256) {
      float g, be, m, v, extra = 0.f; int so, ho;
      if (t < 128)      { g=bn1[t]; be=bn1[128+t]; m=bn1[256+t]; v=bn1[384+t]; so=t; ho=128+t; }
      else if (t < 144) { int u=t-128; g=bn2[u]; be=bn2[16+u]; m=bn2[32+u]; v=bn2[48+u]; so=256+u; ho=272+u; }
      else if (t < 208) { int u=t-144; int L=u>>4, o=u&15; const float* p=sa_bn+L*64;
                          g=p[o]; be=p[16+o]; m=p[32+o]; v=p[48+o];
                          extra=sa_trans_b[L*16+o]; so=288+u; ho=352+u; }
      else if (t < 336) { int u=t-208; g=fuse_bn[u]; be=fuse_bn[128+u]; m=fuse_bn[256+u]; v=fuse_bn[384+u]; so=416+u; ho=544+u; }
      else if (t < 848) { int u=t-336; g=bns1[u]; be=bns1[512+u]; m=bns1[1024+u]; v=bns1[1536+u]; extra=convs1_b[u]; so=672+u; ho=1184+u; }
      else              { int u=t-848; g=bns2[u]; be=bns2[256+u]; m=bns2[512+u]; v=bns2[768+u]; extra=convs2_b[u]; so=1696+u; ho=1952+u; }
      float sc = g * rsqrtf(v + 1e-5f);
      params[so] = sc;
      params[ho] = (extra - m) * sc + be;
    }
  }
}

// ---------------------------------------------------------------- fused conv1(16->128)+bn+relu -> conv2(128->16)+bn+relu -> layer0 k/v
__global__ __launch_bounds__(256) void k_convs(const float* __restrict__ x,
    const float* __restrict__ w1, const float* __restrict__ w2,
    const float* __restrict__ params, const float* __restrict__ qk_w,
    const float* __restrict__ v_w, const float* __restrict__ v_b,
    float* __restrict__ h0, float* __restrict__ kbuf, float* __restrict__ vbufT)
{
  __shared__ float xs[16 * 64];
  __shared__ float ws1[128 * 17];
  __shared__ float ws2[16 * 129];
  __shared__ __align__(16) float h1s[128 * 64];
  __shared__ float hcv[64 * 17];
  __shared__ float qk[64], vw[256], vb[16], sc1[128], sh1[128], sc2[16], sh2[16];
  int t = threadIdx.x;
  int bid = blockIdx.x;                       // 512 = b*32 + chunk(64 cols)
  int b = bid >> 5, n0 = (bid & 31) * 64;
  for (int i = t; i < 1024; i += 256) { int c = i >> 6, col = i & 63; xs[i] = x[((size_t)b * 16 + c) * 2048 + n0 + col]; }
  for (int i = t; i < 2048; i += 256) { int o = i >> 4, c = i & 15;  ws1[o * 17 + c]  = w1[i]; }
  for (int i = t; i < 2048; i += 256) { int o = i >> 7, c = i & 127; ws2[o * 129 + c] = w2[i]; }
  if (t < 64) qk[t] = qk_w[t];
  vw[t] = v_w[t];
  if (t < 16) { vb[t] = v_b[t]; sc2[t] = params[256 + t]; sh2[t] = params[272 + t]; }
  if (t < 128) { sc1[t] = params[t]; sh1[t] = params[128 + t]; }
  __syncthreads();
  int col = t & 63, og = t >> 6;
  float xr[16];
#pragma unroll
  for (int c = 0; c < 16; ++c) xr[c] = xs[c * 64 + col];
#pragma unroll 4
  for (int i = 0; i < 32; ++i) {
    int o = og * 32 + i;
    float s = 0.f;
#pragma unroll
    for (int c = 0; c < 16; ++c) s = fmaf(ws1[o * 17 + c], xr[c], s);
    h1s[o * 64 + col] = relu_(fmaf(s, sc1[o], sh1[o]));
  }
  __syncthreads();
  float a[4] = {0.f, 0.f, 0.f, 0.f};
  for (int c = 0; c < 128; ++c) {
    float hv = h1s[c * 64 + col];
#pragma unroll
    for (int oo = 0; oo < 4; ++oo) a[oo] = fmaf(ws2[(og * 4 + oo) * 129 + c], hv, a[oo]);
  }
#pragma unroll
  for (int oo = 0; oo < 4; ++oo) {
    int o = og * 4 + oo;
    float v = relu_(fmaf(a[oo], sc2[o], sh2[o]));
    h0[((size_t)b * 16 + o) * 2048 + n0 + col] = v;
    hcv[col * 17 + o] = v;
  }
  __syncthreads();
  float hr[16];
#pragma unroll
  for (int c = 0; c < 16; ++c) hr[c] = hcv[col * 17 + c];
#pragma unroll
  for (int i = 0; i < 5; ++i) {
    int u = og * 5 + i;
    const float* W = (u < 4) ? &qk[u * 16] : &vw[(u - 4) * 16];
    float s = (u < 4) ? 0.f : vb[u - 4];
#pragma unroll
    for (int c = 0; c < 16; ++c) s = fmaf(W[c], hr[c], s);
    if (u < 4) kbuf[((size_t)b * 2048 + n0 + col) * 4 + u] = s;
    else       vbufT[((size_t)b * 2048 + n0 + col) * 16 + (u - 4)] = s;
  }
}

// ---------------------------------------------------------------- pass A: row softmax denominators (16 m-splits, atomic combine)
__global__ __launch_bounds__(256) void k_rowstats(const float* __restrict__ kbuf, float* __restrict__ Lb)
{
  __shared__ float4 kch[128];
  int bid = blockIdx.x;                     // 2048 = b*128 + nt*16 + ms
  int b = bid >> 7, nt = (bid >> 4) & 7, ms = bid & 15;
  int t = threadIdx.x;
  const float4* kb = (const float4*)kbuf + b * 2048;
  if (t < 128) kch[t] = kb[ms * 128 + t];
  __syncthreads();
  int n = nt * 256 + t;
  float4 q = kb[n];
  q.x *= LOG2E; q.y *= LOG2E; q.z *= LOG2E; q.w *= LOG2E;
  float L = 0.f;
#pragma unroll 4
  for (int m = 0; m < 128; ++m) {
    float4 k4 = kch[m];
    float s = fmaf(q.x, k4.x, fmaf(q.y, k4.y, fmaf(q.z, k4.z, q.w * k4.w)));
    L += exp2f(s);
  }
  atomicAdd(&Lb[b * 2048 + n], L);
}

// ---------------------------------------------------------------- pass B: full-n MFMA PV, register-resident accumulators
// e[n,m] = exp2(log2e*kn.km - log2 L_n) (<=1) ; parts[b][c][m] = sum_n V[c,n]*e ; row16 = den = sum_n e
__global__ __launch_bounds__(256, 2) void k_attn(const float* __restrict__ kbuf,
    const float* __restrict__ vbufT, const float* __restrict__ Lb, float* __restrict__ parts)
{
  __shared__ __align__(16) float4 skn4[256];      // XOR-swizzled: slot = n ^ ((n>>3)&3)
  __shared__ float lgn[256];
  __shared__ __align__(16) bf16_t vh[16][264];    // V hi, padded rows
  __shared__ __align__(16) bf16_t vl[16][264];    // V lo
  int t = threadIdx.x;
  int bid = blockIdx.x;                     // 512 = b*32 + mc
  int b = bid >> 5, mc = bid & 31;
  int lane = t & 63, w = t >> 6;
  int lg16 = lane >> 4, c = lane & 15;
  int m0 = mc * 64 + w * 16;
  float4 km = ((const float4*)kbuf)[b * 2048 + m0 + c];
  f32x4 acc = {0.f, 0.f, 0.f, 0.f};
  f32x4 acc2 = {0.f, 0.f, 0.f, 0.f};
  bf16x8 ones;
#pragma unroll
  for (int j = 0; j < 8; ++j) ones[j] = (bf16_t)1.0f;

  for (int ci = 0; ci < 8; ++ci) {
    {  // stage: thread t handles n = ci*256 + t
      int n = ci * 256 + t;
      float4 k4 = ((const float4*)kbuf)[b * 2048 + n];
      float4 ks = {k4.x * LOG2E, k4.y * LOG2E, k4.z * LOG2E, k4.w * LOG2E};
      skn4[t ^ ((t >> 3) & 3)] = ks;
      lgn[t] = -__log2f(Lb[b * 2048 + n]);
      const float4* vp = (const float4*)&vbufT[((size_t)b * 2048 + n) * 16];
#pragma unroll
      for (int q = 0; q < 4; ++q) {
        float4 vv = vp[q];
        bf16_t h0 = (bf16_t)vv.x, h1 = (bf16_t)vv.y, h2 = (bf16_t)vv.z, h3 = (bf16_t)vv.w;
        vh[q * 4 + 0][t] = h0; vl[q * 4 + 0][t] = (bf16_t)(vv.x - (float)h0);
        vh[q * 4 + 1][t] = h1; vl[q * 4 + 1][t] = (bf16_t)(vv.y - (float)h1);
        vh[q * 4 + 2][t] = h2; vl[q * 4 + 2][t] = (bf16_t)(vv.z - (float)h2);
        vh[q * 4 + 3][t] = h3; vl[q * 4 + 3][t] = (bf16_t)(vv.w - (float)h3);
      }
    }
    __syncthreads();
#pragma unroll 2
    for (int s = 0; s < 8; ++s) {
      float e[8];
#pragma unroll
      for (int j = 0; j < 8; ++j) {
        int nn = s * 32 + lg16 * 8 + j;
        float4 kp = skn4[nn ^ ((nn >> 3) & 3)];
        e[j] = exp2f(fmaf(km.x, kp.x, fmaf(km.y, kp.y, fmaf(km.z, kp.z, fmaf(km.w, kp.w, lgn[nn])))));
      }
      bf16x8 eh, el;
#pragma unroll
      for (int j = 0; j < 8; ++j) {
        bf16_t h = (bf16_t)e[j];
        eh[j] = h;
        el[j] = (bf16_t)(e[j] - (float)h);
      }
      bf16x8 ah = *(const bf16x8*)&vh[c][s * 32 + lg16 * 8];
      bf16x8 al = *(const bf16x8*)&vl[c][s * 32 + lg16 * 8];
      acc  = __builtin_amdgcn_mfma_f32_16x16x32_bf16(ah, eh, acc, 0, 0, 0);
      acc  = __builtin_amdgcn_mfma_f32_16x16x32_bf16(al, eh, acc, 0, 0, 0);
      acc  = __builtin_amdgcn_mfma_f32_16x16x32_bf16(ah, el, acc, 0, 0, 0);
      acc2 = __builtin_amdgcn_mfma_f32_16x16x32_bf16(ones, eh, acc2, 0, 0, 0);
      acc2 = __builtin_amdgcn_mfma_f32_16x16x32_bf16(ones, el, acc2, 0, 0, 0);
    }
    __syncthreads();
  }
  float* pp = parts + ((size_t)b * 17) * 2048 + m0 + c;
#pragma unroll
  for (int r = 0; r < 4; ++r)
    pp[(size_t)(lg16 * 4 + r) * 2048] = acc[r];
  if (lane < 16) pp[(size_t)16 * 2048] = acc2[0];
}

// ---------------------------------------------------------------- SA epilogue: trans/bn/relu + residual (+ next k/v)
__global__ __launch_bounds__(256) void k_epilogue(const float* __restrict__ parts,
    const float* __restrict__ hin, int hbs, const float* __restrict__ t_w,
    const float* __restrict__ params, int layer, float* __restrict__ hout,
    const float* __restrict__ qk_w, const float* __restrict__ v_w, const float* __restrict__ v_b,
    float* __restrict__ kbuf, float* __restrict__ vbufT)
{
  __shared__ __align__(16) float pd[17 * 64];
  __shared__ float hs[16 * 64];
  __shared__ float dl[16 * 64];
  __shared__ float hv[64 * 17];
  __shared__ float tw[256], qk[64], vw[256], vb[16], sc[16], sh[16];
  int t = threadIdx.x;
  int bid = blockIdx.x;                     // 512 = b*32 + chunk(64 cols)
  int b = bid >> 5, n0 = (bid & 31) * 64;
  tw[t] = t_w[t];
  if (qk_w) { if (t < 64) qk[t] = qk_w[t]; vw[t] = v_w[t]; if (t < 16) vb[t] = v_b[t]; }
  if (t < 16) { sc[t] = params[288 + layer * 16 + t]; sh[t] = params[352 + layer * 16 + t]; }
  for (int i = t; i < 272; i += 256) {
    int r = i >> 4, c4 = (i & 15) << 2;
    *(f32x4*)&pd[r * 64 + c4] = *(const f32x4*)&parts[((size_t)b * 17 + r) * 2048 + n0 + c4];
  }
  for (int i = t; i < 1024; i += 256) {
    int c = i >> 6, col = i & 63;
    hs[i] = hin[(size_t)b * hbs + (size_t)c * 2048 + n0 + col];
  }
  __syncthreads();
  int col = t & 63, g4 = t >> 6;
  float inv = 1.f / (1e-9f + pd[16 * 64 + col]);
#pragma unroll
  for (int j = 0; j < 4; ++j) {
    int c = g4 * 4 + j;
    dl[c * 64 + col] = hs[c * 64 + col] - pd[c * 64 + col] * inv;
  }
  __syncthreads();
#pragma unroll
  for (int j = 0; j < 4; ++j) {
    int o = g4 * 4 + j;
    float y = 0.f;
#pragma unroll
    for (int c = 0; c < 16; ++c) y = fmaf(tw[o * 16 + c], dl[c * 64 + col], y);
    y = relu_(fmaf(y, sc[o], sh[o]));
    float hh = hs[o * 64 + col] + y;
    hout[(size_t)b * 64 * 2048 + (size_t)o * 2048 + n0 + col] = hh;
    hv[col * 17 + o] = hh;
  }
  if (qk_w) {
    __syncthreads();
    float hr[16];
#pragma unroll
    for (int c = 0; c < 16; ++c) hr[c] = hv[col * 17 + c];
#pragma unroll
    for (int i = 0; i < 5; ++i) {
      int u = g4 * 5 + i;
      const float* W = (u < 4) ? &qk[u * 16] : &vw[(u - 4) * 16];
      float s = (u < 4) ? 0.f : vb[u - 4];
#pragma unroll
      for (int c = 0; c < 16; ++c) s = fmaf(W[c], hr[c], s);
      if (u < 4) kbuf[((size_t)b * 2048 + n0 + col) * 4 + u] = s;
      else       vbufT[((size_t)b * 2048 + n0 + col) * 16 + (u - 4)] = s;
    }
  }
}

// ---------------------------------------------------------------- fuse conv (64->128) + bn + leaky relu
__global__ __launch_bounds__(256) void k_fuse(const float* __restrict__ feats, const float* __restrict__ fw,
    const float* __restrict__ params, float* __restrict__ xqqw, bf16_t* __restrict__ gbuf)
{
  __shared__ float ws[128 * 65];
  __shared__ __align__(16) float fst[64 * 64];
  __shared__ float sc[128], sh[128];
  int t = threadIdx.x, bid = blockIdx.x;    // 512 = b*32 + chunk(64 cols)
  int b = bid >> 5, n0 = (bid & 31) * 64;
  for (int i = t; i < 8192; i += 256) { int o = i >> 6, c = i & 63; ws[o * 65 + c] = fw[i]; }
  for (int i = t; i < 4096; i += 256) { int c = i >> 6, col = i & 63; fst[i] = feats[((size_t)b * 64 + c) * 2048 + n0 + col]; }
  if (t < 128) { sc[t] = params[416 + t]; sh[t] = params[544 + t]; }
  __syncthreads();
  int cg = t & 7, og = t >> 3;
  f32x2 acc[4][4];
#pragma unroll
  for (int oo = 0; oo < 4; ++oo)
#pragma unroll
    for (int j = 0; j < 4; ++j) acc[oo][j] = (f32x2){0.f, 0.f};
  for (int c = 0; c < 64; ++c) {
    const f32x2* fp = (const f32x2*)&fst[c * 64 + cg * 8];
    f32x2 f0 = fp[0], f1 = fp[1], f2v = fp[2], f3 = fp[3];
#pragma unroll
    for (int oo = 0; oo < 4; ++oo) {
      float w = ws[(og * 4 + oo) * 65 + c];
      f32x2 wv = {w, w};
      acc[oo][0] += wv * f0; acc[oo][1] += wv * f1;
      acc[oo][2] += wv * f2v; acc[oo][3] += wv * f3;
    }
  }
  float y[4][8];
#pragma unroll
  for (int oo = 0; oo < 4; ++oo) {
    int o = og * 4 + oo;
    float s0 = sc[o], s1 = sh[o];
#pragma unroll
    for (int j = 0; j < 8; ++j) {
      float v = fmaf(acc[oo][j >> 1][j & 1], s0, s1);
      y[oo][j] = v > 0.f ? v : 0.2f * v;
    }
    float4 v0 = {y[oo][0], y[oo][1], y[oo][2], y[oo][3]};
    float4 v1 = {y[oo][4], y[oo][5], y[oo][6], y[oo][7]};
    *(float4*)&xqqw[((size_t)b * 128 + o) * 2048 + n0 + cg * 8] = v0;
    *(float4*)&xqqw[((size_t)b * 128 + o) * 2048 + n0 + cg * 8 + 4] = v1;
  }
#pragma unroll
  for (int j = 0; j < 8; ++j) {
    int col = n0 + cg * 8 + j;
    bf16x4 pk;
    pk[0] = (bf16_t)y[0][j]; pk[1] = (bf16_t)y[1][j];
    pk[2] = (bf16_t)y[2][j]; pk[3] = (bf16_t)y[3][j];
    *(bf16x4*)&gbuf[((size_t)b * 2048 + col) * 128 + og * 4] = pk;
  }
}

// ---------------------------------------------------------------- argmax over n (+ batch-1 channel means)
__global__ __launch_bounds__(256) void k_argmax(const float* __restrict__ xqqw,
    float* __restrict__ xmaxf, float* __restrict__ xavg)
{
  __shared__ float sv[256]; __shared__ int si[256]; __shared__ float ss[256];
  int bo = blockIdx.x;                     // b*128+o
  int b = bo >> 7, o = bo & 127;
  const float* row = xqqw + (size_t)bo * 2048;
  int tid = threadIdx.x;
  float best = -3.4e38f; int bi = 0; float sum = 0.f;
#pragma unroll
  for (int j = 0; j < 8; ++j) {
    int n = j * 256 + tid;
    float v = row[n];
    sum += v;
    if (v > best) { best = v; bi = n; }
  }
  sv[tid] = best; si[tid] = bi; ss[tid] = sum;
  __syncthreads();
  for (int s = 128; s > 0; s >>= 1) {
    if (tid < s) {
      float v2 = sv[tid + s]; int i2 = si[tid + s];
      if (v2 > sv[tid] || (v2 == sv[tid] && i2 < si[tid])) { sv[tid] = v2; si[tid] = i2; }
      ss[tid] += ss[tid + s];
    }
    __syncthreads();
  }
  if (tid == 0) {
    xmaxf[bo] = (float)si[0];
    if (b == 1) xavg[o] = ss[0] * (1.0f / 2048.0f);
  }
}

// ---------------------------------------------------------------- exact fp32 bias from x_max/x_avg rows (replaces g rows 128..287)
__global__ __launch_bounds__(256) void k_bias2(const float* __restrict__ w1,
    const float* __restrict__ xmaxf, const float* __restrict__ xavg,
    const float* __restrict__ params, float* __restrict__ bias2)
{
  int id = blockIdx.x * 256 + threadIdx.x;   // 8192 = o*16 + b
  int o = id >> 4, b = id & 15;
  const float* wr = w1 + (size_t)o * 264;
  float s = 0.f;
  for (int u = 0; u < 128; ++u) s = fmaf(wr[128 + u], xmaxf[b * 128 + u], s);
#pragma unroll
  for (int u = 0; u < 8; ++u)  s = fmaf(wr[256 + u], xavg[b * 8 + u], s);
  bias2[b * 512 + o] = s * params[672 + o];
}

// ---------------------------------------------------------------- bf16 MFMA GEMM: Cout[bn][o] = relu(bn(A[o][:].B[bn][:]) + bias2)
__global__ __launch_bounds__(256) void k_gemm(const bf16_t* __restrict__ A, const bf16_t* __restrict__ Bm,
    const float* __restrict__ scp, const float* __restrict__ shp, const float* __restrict__ bias2,
    bf16_t* __restrict__ Cout, int M, int K, int mtiles)
{
  __shared__ bf16_t At[128 * 32];
  __shared__ bf16_t Bt[128 * 32];
  int tid = threadIdx.x;
  int mt = blockIdx.x % mtiles, ct = blockIdx.x / mtiles;
  int srow = tid >> 2, scol = (tid & 3) << 3;
  const bf16_t* ga = A  + (size_t)(mt * 128 + srow) * K + scol;
  const bf16_t* gb = Bm + (size_t)(ct * 128 + srow) * K + scol;
  int lane = tid & 63, wave = tid >> 6;
  int wr = (wave >> 1) * 64, wc = (wave & 1) * 64;
  int frow = lane & 15, fk = (lane >> 4) * 8;
  const f32x4 z4 = {0.f, 0.f, 0.f, 0.f};
  f32x4 acc[4][4];
#pragma unroll
  for (int i = 0; i < 4; ++i)
#pragma unroll
    for (int j = 0; j < 4; ++j) acc[i][j] = z4;
  uint4 ra0 = *(const uint4*)ga, ra1 = *(const uint4*)(ga + (size_t)64 * K);
  uint4 rb0 = *(const uint4*)gb, rb1 = *(const uint4*)(gb + (size_t)64 * K);
  int ksteps = K >> 5;
  for (int ks = 0; ks < ksteps; ++ks) {
    __syncthreads();
    *(uint4*)&At[tid * 8] = ra0;  *(uint4*)&At[2048 + tid * 8] = ra1;
    *(uint4*)&Bt[tid * 8] = rb0;  *(uint4*)&Bt[2048 + tid * 8] = rb1;
    __syncthreads();
    if (ks + 1 < ksteps) {
      ra0 = *(const uint4*)(ga + (ks + 1) * 32);
      ra1 = *(const uint4*)(ga + (size_t)64 * K + (ks + 1) * 32);
      rb0 = *(const uint4*)(gb + (ks + 1) * 32);
      rb1 = *(const uint4*)(gb + (size_t)64 * K + (ks + 1) * 32);
    }
    bf16x8 af[4], bfr[4];
#pragma unroll
    for (int i = 0; i < 4; ++i) af[i]  = *(const bf16x8*)&At[(wr + i * 16 + frow) * 32 + fk];
#pragma unroll
    for (int j = 0; j < 4; ++j) bfr[j] = *(const bf16x8*)&Bt[(wc + j * 16 + frow) * 32 + fk];
#pragma unroll
    for (int i = 0; i < 4; ++i)
#pragma unroll
      for (int j = 0; j < 4; ++j)
        acc[i][j] = __builtin_amdgcn_mfma_f32_16x16x32_bf16(af[i], bfr[j], acc[i][j], 0, 0, 0);
  }
  int crow = (lane >> 4) * 4, ccol = lane & 15;
#pragma unroll
  for (int i = 0; i < 4; ++i) {
    int o0 = mt * 128 + wr + i * 16 + crow;
    float s0 = scp[o0], s1 = scp[o0+1], s2 = scp[o0+2], s3 = scp[o0+3];
    float t0 = shp[o0], t1 = shp[o0+1], t2 = shp[o0+2], t3 = shp[o0+3];
#pragma unroll
    for (int j = 0; j < 4; ++j) {
      int bn = ct * 128 + wc + j * 16 + ccol;
      float b0 = 0.f, b1 = 0.f, b2 = 0.f, b3 = 0.f;
      if (bias2) {
        const float* bp = bias2 + (size_t)(bn >> 11) * M + o0;
        b0 = bp[0]; b1 = bp[1]; b2 = bp[2]; b3 = bp[3];
      }
      bf16x4 pk;
      pk[0] = (bf16_t)relu_(fmaf(acc[i][j][0], s0, t0 + b0));
      pk[1] = (bf16_t)relu_(fmaf(acc[i][j][1], s1, t1 + b1));
      pk[2] = (bf16_t)relu_(fmaf(acc[i][j][2], s2, t2 + b2));
      pk[3] = (bf16_t)relu_(fmaf(acc[i][j][3], s3, t3 + b3));
      *(bf16x4*)(Cout + (size_t)bn * M + o0) = pk;
    }
  }
}

// ---------------------------------------------------------------- convs3 (256->16) + bias, fp32 out
__global__ __launch_bounds__(256) void k_gemm3(const bf16_t* __restrict__ g2, const float* __restrict__ w3,
    const float* __restrict__ b3, float* __restrict__ out)
{
  __shared__ float wsT[4096];   // [k][o]
  __shared__ float bb[16];
  int t = threadIdx.x;
  for (int i = t; i < 4096; i += 256) { int o = i >> 8, k = i & 255; wsT[k * 16 + o] = w3[i]; }
  if (t < 16) bb[t] = b3[t];
  __syncthreads();
  int col = blockIdx.x * 64 + (t & 63);     // grid 512
  int og = t >> 6;
  int b = col >> 11, n = col & 2047;
  const bf16_t* g = g2 + (size_t)col * 256;
  float acc[4] = {0.f, 0.f, 0.f, 0.f};
  for (int k0 = 0; k0 < 256; k0 += 8) {
    bf16x8 gv8 = *(const bf16x8*)(g + k0);
#pragma unroll
    for (int kk = 0; kk < 8; ++kk) {
      float gv = (float)gv8[kk];
      const float* wr = &wsT[(k0 + kk) * 16 + og * 4];
#pragma unroll
      for (int oo = 0; oo < 4; ++oo) acc[oo] = fmaf(wr[oo], gv, acc[oo]);
    }
  }
  float* op = out + (size_t)b * 16 * 2048 + n;
#pragma unroll
  for (int oo = 0; oo < 4; ++oo) {
    int o = og * 4 + oo;
    op[(size_t)o * 2048] = acc[oo] + bb[o];
  }
}

// ---------------------------------------------------------------- launch
extern "C" void kernel_launch(void* const* d_in, const int* in_sizes, int n_in,
                              void* d_out, int out_size, void* d_ws, size_t ws_size,
                              hipStream_t stream)
{
  const float* x         = (const float*)d_in[0];
  const float* conv1_w   = (const float*)d_in[1];
  const float* bn1       = (const float*)d_in[2];
  const float* conv2_w   = (const float*)d_in[3];
  const float* bn2       = (const float*)d_in[4];
  const float* sa_qk_w   = (const float*)d_in[5];
  const float* sa_v_w    = (const float*)d_in[6];
  const float* sa_v_b    = (const float*)d_in[7];
  const float* sa_trans_w= (const float*)d_in[8];
  const float* sa_trans_b= (const float*)d_in[9];
  const float* sa_bn     = (const float*)d_in[10];
  const float* fuse_w    = (const float*)d_in[11];
  const float* fuse_bn   = (const float*)d_in[12];
  const float* convs1_w  = (const float*)d_in[13];
  const float* convs1_b  = (const float*)d_in[14];
  const float* bns1      = (const float*)d_in[15];
  const float* convs2_w  = (const float*)d_in[16];
  const float* convs2_b  = (const float*)d_in[17];
  const float* bns2      = (const float*)d_in[18];
  const float* convs3_w  = (const float*)d_in[19];
  const float* convs3_b  = (const float*)d_in[20];

  char* ws = (char*)d_ws;
  float*  xqqw  = (float*)(ws + 0);            // 16 MB
  float*  feats = (float*)(ws + 16777216);     // 8 MB
  float*  h0    = (float*)(ws + 25165824);     // 2 MB
  float*  kbuf  = (float*)(ws + 27262976);     // 0.5 MB
  float*  vbufT = (float*)(ws + 27787264);     // 2 MB
  float*  Lbuf  = (float*)(ws + 29884416);     // 512 KB  [4][16][2048]
  float*  parts = (float*)(ws + 31981568);     // 2.23 MB [16][17][2048] f32
  bf16_t* g1    = (bf16_t*)(ws + 0);           // 32 MB, overlays xqqw/feats/h0/attn (dead)
  bf16_t* g2    = (bf16_t*)(ws + 34603008);    // 16 MB
  bf16_t* gbuf  = (bf16_t*)(ws + 51380224);    // 8 MB
  bf16_t* wbuf1 = (bf16_t*)(ws + 67633152);    // 128 KB
  bf16_t* wbuf2 = (bf16_t*)(ws + 67764224);    // 256 KB
  float*  params= (float*)(ws + 68026368);
  float*  xmaxf = (float*)(ws + 68042752);
  float*  xavg  = (float*)(ws + 68050944);
  float*  bias2 = (float*)(ws + 68055040);

  k_prep<<<256, 256, 0, stream>>>(convs1_w, convs2_w, bn1, bn2, sa_bn, sa_trans_b, fuse_bn,
                                  convs1_b, bns1, convs2_b, bns2, wbuf1, wbuf2, params, Lbuf);
  k_convs<<<512, 256, 0, stream>>>(x, conv1_w, conv2_w, params, sa_qk_w, sa_v_w, sa_v_b,
                                   h0, kbuf, vbufT);
  for (int i = 0; i < 4; ++i) {
    float* Lb = Lbuf + (size_t)i * 32768;
    k_rowstats<<<2048, 256, 0, stream>>>(kbuf, Lb);
    k_attn<<<512, 256, 0, stream>>>(kbuf, vbufT, Lb, parts);
    const float* hin = (i == 0) ? h0 : (feats + (size_t)(i - 1) * 16 * 2048);
    int hbs = (i == 0) ? 16 * 2048 : 64 * 2048;
    bool last = (i == 3);
    k_epilogue<<<512, 256, 0, stream>>>(parts, hin, hbs, sa_trans_w + i * 256, params, i,
        feats + (size_t)i * 16 * 2048,
        last ? nullptr : sa_qk_w + (i + 1) * 64,
        last ? nullptr : sa_v_w + (i + 1) * 256,
        last ? nullptr : sa_v_b + (i + 1) * 16,
        kbuf, vbufT);
  }
  k_fuse<<<512, 256, 0, stream>>>(feats, fuse_w, params, xqqw, gbuf);
  k_argmax<<<2048, 256, 0, stream>>>(xqqw, xmaxf, xavg);
  k_bias2<<<32, 256, 0, stream>>>(convs1_w, xmaxf, xavg, params, bias2);
  k_gemm<<<1024, 256, 0, stream>>>(wbuf1, gbuf, params + 672, params + 1184, bias2, g1, 512, 128, 4);
  k_gemm<<<512, 256, 0, stream>>>(wbuf2, g1, params + 1696, params + 1952, nullptr, g2, 256, 512, 2);
  k_gemm3<<<512, 256, 0, stream>>>(g2, convs3_w, convs3_b, (float*)d_out);
}

// Round 9
// 463.386 us; speedup vs baseline: 1.9725x; 1.0717x over previous
//
#include <hip/hip_runtime.h>
#include <stdint.h>

typedef __bf16 bf16_t;
typedef __bf16 bf16x8 __attribute__((ext_vector_type(8)));
typedef __bf16 bf16x4 __attribute__((ext_vector_type(4)));
typedef float f32x4 __attribute__((ext_vector_type(4)));
typedef float f32x2 __attribute__((ext_vector_type(2)));

#define LOG2E 1.4426950408889634f

__device__ __forceinline__ float relu_(float v) { return v > 0.f ? v : 0.f; }

// ---------------------------------------------------------------- prep
// params layout (floats):
// 0 bn1_scale[128] |128 bn1_shift[128] |256 bn2_scale[16] |272 bn2_shift[16]
// 288 sa_scale[64] |352 sa_shift[64] |416 fuse_scale[128] |544 fuse_shift[128]
// 672 bns1_scale[512] |1184 bns1_shift[512] |1696 bns2_scale[256] |1952 bns2_shift[256]
__global__ __launch_bounds__(256) void k_prep(
    const float* __restrict__ convs1_w, const float* __restrict__ convs2_w,
    const float* __restrict__ bn1, const float* __restrict__ bn2,
    const float* __restrict__ sa_bn, const float* __restrict__ sa_trans_b,
    const float* __restrict__ fuse_bn, const float* __restrict__ convs1_b,
    const float* __restrict__ bns1, const float* __restrict__ convs2_b,
    const float* __restrict__ bns2,
    bf16_t* __restrict__ wbuf1, bf16_t* __restrict__ wbuf2, float* __restrict__ params,
    float* __restrict__ Lbuf)
{
  int idx = blockIdx.x * 256 + threadIdx.x;
  // zero per-layer softmax row-sum accumulators L[4][16][2048]
  Lbuf[idx] = 0.f;
  Lbuf[idx + 65536] = 0.f;
  for (int it = 0; it < 3; ++it) {
    int i = idx + it * 65536;
    if (i < 65536) {                        // wbuf1 [512][128] = first 128 cols of convs1_w
      int o = i >> 7, c = i & 127;
      wbuf1[i] = (bf16_t)convs1_w[o * 264 + c];
    } else if (i < 65536 + 131072) {        // wbuf2 [256][512]
      int j = i - 65536;
      wbuf2[j] = (bf16_t)convs2_w[j];
    }
  }
  if (blockIdx.x == 0) {
    for (int t = threadIdx.x; t < 1104; t += 256) {
      float g, be, m, v, extra = 0.f; int so, ho;
      if (t < 128)      { g=bn1[t]; be=bn1[128+t]; m=bn1[256+t]; v=bn1[384+t]; so=t; ho=128+t; }
      else if (t < 144) { int u=t-128; g=bn2[u]; be=bn2[16+u]; m=bn2[32+u]; v=bn2[48+u]; so=256+u; ho=272+u; }
      else if (t < 208) { int u=t-144; int L=u>>4, o=u&15; const float* p=sa_bn+L*64;
                          g=p[o]; be=p[16+o]; m=p[32+o]; v=p[48+o];
                          extra=sa_trans_b[L*16+o]; so=288+u; ho=352+u; }
      else if (t < 336) { int u=t-208; g=fuse_bn[u]; be=fuse_bn[128+u]; m=fuse_bn[256+u]; v=fuse_bn[384+u]; so=416+u; ho=544+u; }
      else if (t < 848) { int u=t-336; g=bns1[u]; be=bns1[512+u]; m=bns1[1024+u]; v=bns1[1536+u]; extra=convs1_b[u]; so=672+u; ho=1184+u; }
      else              { int u=t-848; g=bns2[u]; be=bns2[256+u]; m=bns2[512+u]; v=bns2[768+u]; extra=convs2_b[u]; so=1696+u; ho=1952+u; }
      float sc = g * rsqrtf(v + 1e-5f);
      params[so] = sc;
      params[ho] = (extra - m) * sc + be;
    }
  }
}

// ---------------------------------------------------------------- fused conv1(16->128)+bn+relu -> conv2(128->16)+bn+relu -> layer0 k/v
__global__ __launch_bounds__(256) void k_convs(const float* __restrict__ x,
    const float* __restrict__ w1, const float* __restrict__ w2,
    const float* __restrict__ params, const float* __restrict__ qk_w,
    const float* __restrict__ v_w, const float* __restrict__ v_b,
    float* __restrict__ h0, float* __restrict__ kbuf, float* __restrict__ vbufT)
{
  __shared__ float xs[16 * 64];
  __shared__ float ws1[128 * 17];
  __shared__ float ws2[16 * 129];
  __shared__ __align__(16) float h1s[128 * 64];
  __shared__ float hcv[64 * 17];
  __shared__ float qk[64], vw[256], vb[16], sc1[128], sh1[128], sc2[16], sh2[16];
  int t = threadIdx.x;
  int bid = blockIdx.x;                       // 512 = b*32 + chunk(64 cols)
  int b = bid >> 5, n0 = (bid & 31) * 64;
  for (int i = t; i < 1024; i += 256) { int c = i >> 6, col = i & 63; xs[i] = x[((size_t)b * 16 + c) * 2048 + n0 + col]; }
  for (int i = t; i < 2048; i += 256) { int o = i >> 4, c = i & 15;  ws1[o * 17 + c]  = w1[i]; }
  for (int i = t; i < 2048; i += 256) { int o = i >> 7, c = i & 127; ws2[o * 129 + c] = w2[i]; }
  if (t < 64) qk[t] = qk_w[t];
  vw[t] = v_w[t];
  if (t < 16) { vb[t] = v_b[t]; sc2[t] = params[256 + t]; sh2[t] = params[272 + t]; }
  if (t < 128) { sc1[t] = params[t]; sh1[t] = params[128 + t]; }
  __syncthreads();
  int col = t & 63, og = t >> 6;
  float xr[16];
#pragma unroll
  for (int c = 0; c < 16; ++c) xr[c] = xs[c * 64 + col];
#pragma unroll 4
  for (int i = 0; i < 32; ++i) {
    int o = og * 32 + i;
    float s = 0.f;
#pragma unroll
    for (int c = 0; c < 16; ++c) s = fmaf(ws1[o * 17 + c], xr[c], s);
    h1s[o * 64 + col] = relu_(fmaf(s, sc1[o], sh1[o]));
  }
  __syncthreads();
  float a[4] = {0.f, 0.f, 0.f, 0.f};
  for (int c = 0; c < 128; ++c) {
    float hv = h1s[c * 64 + col];
#pragma unroll
    for (int oo = 0; oo < 4; ++oo) a[oo] = fmaf(ws2[(og * 4 + oo) * 129 + c], hv, a[oo]);
  }
#pragma unroll
  for (int oo = 0; oo < 4; ++oo) {
    int o = og * 4 + oo;
    float v = relu_(fmaf(a[oo], sc2[o], sh2[o]));
    h0[((size_t)b * 16 + o) * 2048 + n0 + col] = v;
    hcv[col * 17 + o] = v;
  }
  __syncthreads();
  float hr[16];
#pragma unroll
  for (int c = 0; c < 16; ++c) hr[c] = hcv[col * 17 + c];
#pragma unroll
  for (int i = 0; i < 5; ++i) {
    int u = og * 5 + i;
    const float* W = (u < 4) ? &qk[u * 16] : &vw[(u - 4) * 16];
    float s = (u < 4) ? 0.f : vb[u - 4];
#pragma unroll
    for (int c = 0; c < 16; ++c) s = fmaf(W[c], hr[c], s);
    if (u < 4) kbuf[((size_t)b * 2048 + n0 + col) * 4 + u] = s;
    else       vbufT[((size_t)b * 2048 + n0 + col) * 16 + (u - 4)] = s;
  }
}

// ---------------------------------------------------------------- pass A: row softmax denominators (16 m-splits, atomic combine)
__global__ __launch_bounds__(256) void k_rowstats(const float* __restrict__ kbuf, float* __restrict__ Lb)
{
  __shared__ float4 kch[128];
  int bid = blockIdx.x;                     // 2048 = b*128 + nt*16 + ms
  int b = bid >> 7, nt = (bid >> 4) & 7, ms = bid & 15;
  int t = threadIdx.x;
  const float4* kb = (const float4*)kbuf + b * 2048;
  if (t < 128) kch[t] = kb[ms * 128 + t];
  __syncthreads();
  int n = nt * 256 + t;
  float4 q = kb[n];
  q.x *= LOG2E; q.y *= LOG2E; q.z *= LOG2E; q.w *= LOG2E;
  float L = 0.f;
#pragma unroll 4
  for (int m = 0; m < 128; ++m) {
    float4 k4 = kch[m];
    float s = fmaf(q.x, k4.x, fmaf(q.y, k4.y, fmaf(q.z, k4.z, q.w * k4.w)));
    L += exp2f(s);
  }
  atomicAdd(&Lb[b * 2048 + n], L);
}

// ---------------------------------------------------------------- pass B: MFMA PV, 4-way n-split (512 n per block), register accumulators
// e[n,m] = exp2(log2e*kn.km - log2 L_n) (<=1) ; parts[ns][b][c][m] = sum_n V[c,n]*e ; row16 = den
__global__ __launch_bounds__(256, 2) void k_attn(const float* __restrict__ kbuf,
    const float* __restrict__ vbufT, const float* __restrict__ Lb, float* __restrict__ parts)
{
  __shared__ __align__(16) float4 skn4[256];      // XOR-swizzled: slot = n ^ ((n>>3)&3)
  __shared__ __align__(16) float lgn[256];
  __shared__ __align__(16) bf16_t vh[16][264];    // V hi, padded rows
  __shared__ __align__(16) bf16_t vl[16][264];    // V lo
  int t = threadIdx.x;
  int bid = blockIdx.x;                     // 2048 = b*128 + ns*32 + mc
  int b = bid >> 7, ns = (bid >> 5) & 3, mc = bid & 31;
  int lane = t & 63, w = t >> 6;
  int lg16 = lane >> 4, c = lane & 15;
  int m0 = mc * 64 + w * 16;
  float4 km = ((const float4*)kbuf)[b * 2048 + m0 + c];
  f32x4 acc = {0.f, 0.f, 0.f, 0.f};
  f32x4 acc2 = {0.f, 0.f, 0.f, 0.f};
  bf16x8 ones;
#pragma unroll
  for (int j = 0; j < 8; ++j) ones[j] = (bf16_t)1.0f;

  for (int ci = 0; ci < 2; ++ci) {
    {  // stage: thread t handles n = ns*512 + ci*256 + t  (block covers 512 n)
      int n = ns * 512 + ci * 256 + t;
      float4 k4 = ((const float4*)kbuf)[b * 2048 + n];
      float4 ks = {k4.x * LOG2E, k4.y * LOG2E, k4.z * LOG2E, k4.w * LOG2E};
      skn4[t ^ ((t >> 3) & 3)] = ks;
      lgn[t] = -__log2f(Lb[b * 2048 + n]);
      const float4* vp = (const float4*)&vbufT[((size_t)b * 2048 + n) * 16];
#pragma unroll
      for (int q = 0; q < 4; ++q) {
        float4 vv = vp[q];
        bf16_t h0 = (bf16_t)vv.x, h1 = (bf16_t)vv.y, h2 = (bf16_t)vv.z, h3 = (bf16_t)vv.w;
        vh[q * 4 + 0][t] = h0; vl[q * 4 + 0][t] = (bf16_t)(vv.x - (float)h0);
        vh[q * 4 + 1][t] = h1; vl[q * 4 + 1][t] = (bf16_t)(vv.y - (float)h1);
        vh[q * 4 + 2][t] = h2; vl[q * 4 + 2][t] = (bf16_t)(vv.z - (float)h2);
        vh[q * 4 + 3][t] = h3; vl[q * 4 + 3][t] = (bf16_t)(vv.w - (float)h3);
      }
    }
    __syncthreads();
#pragma unroll 2
    for (int s = 0; s < 8; ++s) {
      int nn0 = s * 32 + lg16 * 8;
      f32x4 lg0 = *(const f32x4*)&lgn[nn0];
      f32x4 lg1 = *(const f32x4*)&lgn[nn0 + 4];
      float e[8];
#pragma unroll
      for (int j = 0; j < 8; ++j) {
        int nn = nn0 + j;
        float4 kp = skn4[nn ^ lg16];
        float lg = (j < 4) ? lg0[j & 3] : lg1[j & 3];
        e[j] = exp2f(fmaf(km.x, kp.x, fmaf(km.y, kp.y, fmaf(km.z, kp.z, fmaf(km.w, kp.w, lg)))));
      }
      bf16x8 eh, el;
#pragma unroll
      for (int j = 0; j < 8; ++j) {
        bf16_t h = (bf16_t)e[j];
        eh[j] = h;
        el[j] = (bf16_t)(e[j] - (float)h);
      }
      bf16x8 ah = *(const bf16x8*)&vh[c][nn0];
      bf16x8 al = *(const bf16x8*)&vl[c][nn0];
      acc  = __builtin_amdgcn_mfma_f32_16x16x32_bf16(ah, eh, acc, 0, 0, 0);
      acc  = __builtin_amdgcn_mfma_f32_16x16x32_bf16(al, eh, acc, 0, 0, 0);
      acc  = __builtin_amdgcn_mfma_f32_16x16x32_bf16(ah, el, acc, 0, 0, 0);
      acc2 = __builtin_amdgcn_mfma_f32_16x16x32_bf16(ones, eh, acc2, 0, 0, 0);
      acc2 = __builtin_amdgcn_mfma_f32_16x16x32_bf16(ones, el, acc2, 0, 0, 0);
    }
    __syncthreads();
  }
  float* pp = parts + ((size_t)(ns * 16 + b) * 17) * 2048 + m0 + c;
#pragma unroll
  for (int r = 0; r < 4; ++r)
    pp[(size_t)(lg16 * 4 + r) * 2048] = acc[r];
  if (lane < 16) pp[(size_t)16 * 2048] = acc2[0];
}

// ---------------------------------------------------------------- SA epilogue: combine 4 splits + trans/bn/relu + residual (+ next k/v)
__global__ __launch_bounds__(256) void k_epilogue(const float* __restrict__ parts,
    const float* __restrict__ hin, int hbs, const float* __restrict__ t_w,
    const float* __restrict__ params, int layer, float* __restrict__ hout,
    const float* __restrict__ qk_w, const float* __restrict__ v_w, const float* __restrict__ v_b,
    float* __restrict__ kbuf, float* __restrict__ vbufT)
{
  __shared__ __align__(16) float pd[17 * 64];
  __shared__ float hs[16 * 64];
  __shared__ float dl[16 * 64];
  __shared__ float hv[64 * 17];
  __shared__ float tw[256], qk[64], vw[256], vb[16], sc[16], sh[16];
  int t = threadIdx.x;
  int bid = blockIdx.x;                     // 512 = b*32 + chunk(64 cols)
  int b = bid >> 5, n0 = (bid & 31) * 64;
  tw[t] = t_w[t];
  if (qk_w) { if (t < 64) qk[t] = qk_w[t]; vw[t] = v_w[t]; if (t < 16) vb[t] = v_b[t]; }
  if (t < 16) { sc[t] = params[288 + layer * 16 + t]; sh[t] = params[352 + layer * 16 + t]; }
  for (int i = t; i < 272; i += 256) {
    int r = i >> 4, c4 = (i & 15) << 2;
    f32x4 s = {0.f, 0.f, 0.f, 0.f};
#pragma unroll
    for (int sp = 0; sp < 4; ++sp)
      s += *(const f32x4*)&parts[((size_t)(sp * 16 + b) * 17 + r) * 2048 + n0 + c4];
    *(f32x4*)&pd[r * 64 + c4] = s;
  }
  for (int i = t; i < 1024; i += 256) {
    int c = i >> 6, col = i & 63;
    hs[i] = hin[(size_t)b * hbs + (size_t)c * 2048 + n0 + col];
  }
  __syncthreads();
  int col = t & 63, g4 = t >> 6;
  float inv = 1.f / (1e-9f + pd[16 * 64 + col]);
#pragma unroll
  for (int j = 0; j < 4; ++j) {
    int c = g4 * 4 + j;
    dl[c * 64 + col] = hs[c * 64 + col] - pd[c * 64 + col] * inv;
  }
  __syncthreads();
#pragma unroll
  for (int j = 0; j < 4; ++j) {
    int o = g4 * 4 + j;
    float y = 0.f;
#pragma unroll
    for (int c = 0; c < 16; ++c) y = fmaf(tw[o * 16 + c], dl[c * 64 + col], y);
    y = relu_(fmaf(y, sc[o], sh[o]));
    float hh = hs[o * 64 + col] + y;
    hout[(size_t)b * 64 * 2048 + (size_t)o * 2048 + n0 + col] = hh;
    hv[col * 17 + o] = hh;
  }
  if (qk_w) {
    __syncthreads();
    float hr[16];
#pragma unroll
    for (int c = 0; c < 16; ++c) hr[c] = hv[col * 17 + c];
#pragma unroll
    for (int i = 0; i < 5; ++i) {
      int u = g4 * 5 + i;
      const float* W = (u < 4) ? &qk[u * 16] : &vw[(u - 4) * 16];
      float s = (u < 4) ? 0.f : vb[u - 4];
#pragma unroll
      for (int c = 0; c < 16; ++c) s = fmaf(W[c], hr[c], s);
      if (u < 4) kbuf[((size_t)b * 2048 + n0 + col) * 4 + u] = s;
      else       vbufT[((size_t)b * 2048 + n0 + col) * 16 + (u - 4)] = s;
    }
  }
}

// ---------------------------------------------------------------- fuse conv (64->128) + bn + leaky relu
__global__ __launch_bounds__(256) void k_fuse(const float* __restrict__ feats, const float* __restrict__ fw,
    const float* __restrict__ params, float* __restrict__ xqqw, bf16_t* __restrict__ gbuf)
{
  __shared__ float ws[128 * 65];
  __shared__ __align__(16) float fst[64 * 64];
  __shared__ float sc[128], sh[128];
  int t = threadIdx.x, bid = blockIdx.x;    // 512 = b*32 + chunk(64 cols)
  int b = bid >> 5, n0 = (bid & 31) * 64;
  for (int i = t; i < 8192; i += 256) { int o = i >> 6, c = i & 63; ws[o * 65 + c] = fw[i]; }
  for (int i = t; i < 4096; i += 256) { int c = i >> 6, col = i & 63; fst[i] = feats[((size_t)b * 64 + c) * 2048 + n0 + col]; }
  if (t < 128) { sc[t] = params[416 + t]; sh[t] = params[544 + t]; }
  __syncthreads();
  int cg = t & 7, og = t >> 3;
  f32x2 acc[4][4];
#pragma unroll
  for (int oo = 0; oo < 4; ++oo)
#pragma unroll
    for (int j = 0; j < 4; ++j) acc[oo][j] = (f32x2){0.f, 0.f};
  for (int c = 0; c < 64; ++c) {
    const f32x2* fp = (const f32x2*)&fst[c * 64 + cg * 8];
    f32x2 f0 = fp[0], f1 = fp[1], f2v = fp[2], f3 = fp[3];
#pragma unroll
    for (int oo = 0; oo < 4; ++oo) {
      float w = ws[(og * 4 + oo) * 65 + c];
      f32x2 wv = {w, w};
      acc[oo][0] += wv * f0; acc[oo][1] += wv * f1;
      acc[oo][2] += wv * f2v; acc[oo][3] += wv * f3;
    }
  }
  float y[4][8];
#pragma unroll
  for (int oo = 0; oo < 4; ++oo) {
    int o = og * 4 + oo;
    float s0 = sc[o], s1 = sh[o];
#pragma unroll
    for (int j = 0; j < 8; ++j) {
      float v = fmaf(acc[oo][j >> 1][j & 1], s0, s1);
      y[oo][j] = v > 0.f ? v : 0.2f * v;
    }
    float4 v0 = {y[oo][0], y[oo][1], y[oo][2], y[oo][3]};
    float4 v1 = {y[oo][4], y[oo][5], y[oo][6], y[oo][7]};
    *(float4*)&xqqw[((size_t)b * 128 + o) * 2048 + n0 + cg * 8] = v0;
    *(float4*)&xqqw[((size_t)b * 128 + o) * 2048 + n0 + cg * 8 + 4] = v1;
  }
#pragma unroll
  for (int j = 0; j < 8; ++j) {
    int col = n0 + cg * 8 + j;
    bf16x4 pk;
    pk[0] = (bf16_t)y[0][j]; pk[1] = (bf16_t)y[1][j];
    pk[2] = (bf16_t)y[2][j]; pk[3] = (bf16_t)y[3][j];
    *(bf16x4*)&gbuf[((size_t)b * 2048 + col) * 128 + og * 4] = pk;
  }
}

// ---------------------------------------------------------------- argmax over n (+ batch-1 channel means)
__global__ __launch_bounds__(256) void k_argmax(const float* __restrict__ xqqw,
    float* __restrict__ xmaxf, float* __restrict__ xavg)
{
  __shared__ float sv[256]; __shared__ int si[256]; __shared__ float ss[256];
  int bo = blockIdx.x;                     // b*128+o
  int b = bo >> 7, o = bo & 127;
  const float* row = xqqw + (size_t)bo * 2048;
  int tid = threadIdx.x;
  float best = -3.4e38f; int bi = 0; float sum = 0.f;
#pragma unroll
  for (int j = 0; j < 8; ++j) {
    int n = j * 256 + tid;
    float v = row[n];
    sum += v;
    if (v > best) { best = v; bi = n; }
  }
  sv[tid] = best; si[tid] = bi; ss[tid] = sum;
  __syncthreads();
  for (int s = 128; s > 0; s >>= 1) {
    if (tid < s) {
      float v2 = sv[tid + s]; int i2 = si[tid + s];
      if (v2 > sv[tid] || (v2 == sv[tid] && i2 < si[tid])) { sv[tid] = v2; si[tid] = i2; }
      ss[tid] += ss[tid + s];
    }
    __syncthreads();
  }
  if (tid == 0) {
    xmaxf[bo] = (float)si[0];
    if (b == 1) xavg[o] = ss[0] * (1.0f / 2048.0f);
  }
}

// ---------------------------------------------------------------- exact fp32 bias from x_max/x_avg rows (replaces g rows 128..287)
__global__ __launch_bounds__(256) void k_bias2(const float* __restrict__ w1,
    const float* __restrict__ xmaxf, const float* __restrict__ xavg,
    const float* __restrict__ params, float* __restrict__ bias2)
{
  int id = blockIdx.x * 256 + threadIdx.x;   // 8192 = o*16 + b
  int o = id >> 4, b = id & 15;
  const float* wr = w1 + (size_t)o * 264;
  float s = 0.f;
  for (int u = 0; u < 128; ++u) s = fmaf(wr[128 + u], xmaxf[b * 128 + u], s);
#pragma unroll
  for (int u = 0; u < 8; ++u)  s = fmaf(wr[256 + u], xavg[b * 8 + u], s);
  bias2[b * 512 + o] = s * params[672 + o];
}

// ---------------------------------------------------------------- bf16 MFMA GEMM: Cout[bn][o] = relu(bn(A[o][:].B[bn][:]) + bias2)
__global__ __launch_bounds__(256) void k_gemm(const bf16_t* __restrict__ A, const bf16_t* __restrict__ Bm,
    const float* __restrict__ scp, const float* __restrict__ shp, const float* __restrict__ bias2,
    bf16_t* __restrict__ Cout, int M, int K, int mtiles)
{
  __shared__ bf16_t At[128 * 32];
  __shared__ bf16_t Bt[128 * 32];
  int tid = threadIdx.x;
  int mt = blockIdx.x % mtiles, ct = blockIdx.x / mtiles;
  int srow = tid >> 2, scol = (tid & 3) << 3;
  const bf16_t* ga = A  + (size_t)(mt * 128 + srow) * K + scol;
  const bf16_t* gb = Bm + (size_t)(ct * 128 + srow) * K + scol;
  int lane = tid & 63, wave = tid >> 6;
  int wr = (wave >> 1) * 64, wc = (wave & 1) * 64;
  int frow = lane & 15, fk = (lane >> 4) * 8;
  const f32x4 z4 = {0.f, 0.f, 0.f, 0.f};
  f32x4 acc[4][4];
#pragma unroll
  for (int i = 0; i < 4; ++i)
#pragma unroll
    for (int j = 0; j < 4; ++j) acc[i][j] = z4;
  uint4 ra0 = *(const uint4*)ga, ra1 = *(const uint4*)(ga + (size_t)64 * K);
  uint4 rb0 = *(const uint4*)gb, rb1 = *(const uint4*)(gb + (size_t)64 * K);
  int ksteps = K >> 5;
  for (int ks = 0; ks < ksteps; ++ks) {
    __syncthreads();
    *(uint4*)&At[tid * 8] = ra0;  *(uint4*)&At[2048 + tid * 8] = ra1;
    *(uint4*)&Bt[tid * 8] = rb0;  *(uint4*)&Bt[2048 + tid * 8] = rb1;
    __syncthreads();
    if (ks + 1 < ksteps) {
      ra0 = *(const uint4*)(ga + (ks + 1) * 32);
      ra1 = *(const uint4*)(ga + (size_t)64 * K + (ks + 1) * 32);
      rb0 = *(const uint4*)(gb + (ks + 1) * 32);
      rb1 = *(const uint4*)(gb + (size_t)64 * K + (ks + 1) * 32);
    }
    bf16x8 af[4], bfr[4];
#pragma unroll
    for (int i = 0; i < 4; ++i) af[i]  = *(const bf16x8*)&At[(wr + i * 16 + frow) * 32 + fk];
#pragma unroll
    for (int j = 0; j < 4; ++j) bfr[j] = *(const bf16x8*)&Bt[(wc + j * 16 + frow) * 32 + fk];
#pragma unroll
    for (int i = 0; i < 4; ++i)
#pragma unroll
      for (int j = 0; j < 4; ++j)
        acc[i][j] = __builtin_amdgcn_mfma_f32_16x16x32_bf16(af[i], bfr[j], acc[i][j], 0, 0, 0);
  }
  int crow = (lane >> 4) * 4, ccol = lane & 15;
#pragma unroll
  for (int i = 0; i < 4; ++i) {
    int o0 = mt * 128 + wr + i * 16 + crow;
    float s0 = scp[o0], s1 = scp[o0+1], s2 = scp[o0+2], s3 = scp[o0+3];
    float t0 = shp[o0], t1 = shp[o0+1], t2 = shp[o0+2], t3 = shp[o0+3];
#pragma unroll
    for (int j = 0; j < 4; ++j) {
      int bn = ct * 128 + wc + j * 16 + ccol;
      float b0 = 0.f, b1 = 0.f, b2 = 0.f, b3 = 0.f;
      if (bias2) {
        const float* bp = bias2 + (size_t)(bn >> 11) * M + o0;
        b0 = bp[0]; b1 = bp[1]; b2 = bp[2]; b3 = bp[3];
      }
      bf16x4 pk;
      pk[0] = (bf16_t)relu_(fmaf(acc[i][j][0], s0, t0 + b0));
      pk[1] = (bf16_t)relu_(fmaf(acc[i][j][1], s1, t1 + b1));
      pk[2] = (bf16_t)relu_(fmaf(acc[i][j][2], s2, t2 + b2));
      pk[3] = (bf16_t)relu_(fmaf(acc[i][j][3], s3, t3 + b3));
      *(bf16x4*)(Cout + (size_t)bn * M + o0) = pk;
    }
  }
}

// ---------------------------------------------------------------- convs3 (256->16) + bias, fp32 out
__global__ __launch_bounds__(256) void k_gemm3(const bf16_t* __restrict__ g2, const float* __restrict__ w3,
    const float* __restrict__ b3, float* __restrict__ out)
{
  __shared__ float wsT[4096];   // [k][o]
  __shared__ float bb[16];
  int t = threadIdx.x;
  for (int i = t; i < 4096; i += 256) { int o = i >> 8, k = i & 255; wsT[k * 16 + o] = w3[i]; }
  if (t < 16) bb[t] = b3[t];
  __syncthreads();
  int col = blockIdx.x * 64 + (t & 63);     // grid 512
  int og = t >> 6;
  int b = col >> 11, n = col & 2047;
  const bf16_t* g = g2 + (size_t)col * 256;
  float acc[4] = {0.f, 0.f, 0.f, 0.f};
  for (int k0 = 0; k0 < 256; k0 += 8) {
    bf16x8 gv8 = *(const bf16x8*)(g + k0);
#pragma unroll
    for (int kk = 0; kk < 8; ++kk) {
      float gv = (float)gv8[kk];
      const float* wr = &wsT[(k0 + kk) * 16 + og * 4];
#pragma unroll
      for (int oo = 0; oo < 4; ++oo) acc[oo] = fmaf(wr[oo], gv, acc[oo]);
    }
  }
  float* op = out + (size_t)b * 16 * 2048 + n;
#pragma unroll
  for (int oo = 0; oo < 4; ++oo) {
    int o = og * 4 + oo;
    op[(size_t)o * 2048] = acc[oo] + bb[o];
  }
}

// ---------------------------------------------------------------- launch
extern "C" void kernel_launch(void* const* d_in, const int* in_sizes, int n_in,
                              void* d_out, int out_size, void* d_ws, size_t ws_size,
                              hipStream_t stream)
{
  const float* x         = (const float*)d_in[0];
  const float* conv1_w   = (const float*)d_in[1];
  const float* bn1       = (const float*)d_in[2];
  const float* conv2_w   = (const float*)d_in[3];
  const float* bn2       = (const float*)d_in[4];
  const float* sa_qk_w   = (const float*)d_in[5];
  const float* sa_v_w    = (const float*)d_in[6];
  const float* sa_v_b    = (const float*)d_in[7];
  const float* sa_trans_w= (const float*)d_in[8];
  const float* sa_trans_b= (const float*)d_in[9];
  const float* sa_bn     = (const float*)d_in[10];
  const float* fuse_w    = (const float*)d_in[11];
  const float* fuse_bn   = (const float*)d_in[12];
  const float* convs1_w  = (const float*)d_in[13];
  const float* convs1_b  = (const float*)d_in[14];
  const float* bns1      = (const float*)d_in[15];
  const float* convs2_w  = (const float*)d_in[16];
  const float* convs2_b  = (const float*)d_in[17];
  const float* bns2      = (const float*)d_in[18];
  const float* convs3_w  = (const float*)d_in[19];
  const float* convs3_b  = (const float*)d_in[20];

  char* ws = (char*)d_ws;
  float*  xqqw  = (float*)(ws + 0);            // 16 MB
  float*  feats = (float*)(ws + 16777216);     // 8 MB
  float*  h0    = (float*)(ws + 25165824);     // 2 MB
  float*  kbuf  = (float*)(ws + 27262976);     // 0.5 MB
  float*  vbufT = (float*)(ws + 27787264);     // 2 MB
  float*  Lbuf  = (float*)(ws + 29884416);     // 512 KB  [4][16][2048]
  float*  parts = (float*)(ws + 31981568);     // 8.92 MB [4][16][17][2048] f32
  bf16_t* g1    = (bf16_t*)(ws + 0);           // 32 MB, overlays xqqw/feats/h0/attn (dead)
  bf16_t* g2    = (bf16_t*)(ws + 41943040);    // 16 MB (after parts)
  bf16_t* gbuf  = (bf16_t*)(ws + 58720256);    // 8 MB
  bf16_t* wbuf1 = (bf16_t*)(ws + 67633152);    // 128 KB
  bf16_t* wbuf2 = (bf16_t*)(ws + 67764224);    // 256 KB
  float*  params= (float*)(ws + 68026368);
  float*  xmaxf = (float*)(ws + 68042752);
  float*  xavg  = (float*)(ws + 68050944);
  float*  bias2 = (float*)(ws + 68055040);

  k_prep<<<256, 256, 0, stream>>>(convs1_w, convs2_w, bn1, bn2, sa_bn, sa_trans_b, fuse_bn,
                                  convs1_b, bns1, convs2_b, bns2, wbuf1, wbuf2, params, Lbuf);
  k_convs<<<512, 256, 0, stream>>>(x, conv1_w, conv2_w, params, sa_qk_w, sa_v_w, sa_v_b,
                                   h0, kbuf, vbufT);
  for (int i = 0; i < 4; ++i) {
    float* Lb = Lbuf + (size_t)i * 32768;
    k_rowstats<<<2048, 256, 0, stream>>>(kbuf, Lb);
    k_attn<<<2048, 256, 0, stream>>>(kbuf, vbufT, Lb, parts);
    const float* hin = (i == 0) ? h0 : (feats + (size_t)(i - 1) * 16 * 2048);
    int hbs = (i == 0) ? 16 * 2048 : 64 * 2048;
    bool last = (i == 3);
    k_epilogue<<<512, 256, 0, stream>>>(parts, hin, hbs, sa_trans_w + i * 256, params, i,
        feats + (size_t)i * 16 * 2048,
        last ? nullptr : sa_qk_w + (i + 1) * 64,
        last ? nullptr : sa_v_w + (i + 1) * 256,
        last ? nullptr : sa_v_b + (i + 1) * 16,
        kbuf, vbufT);
  }
  k_fuse<<<512, 256, 0, stream>>>(feats, fuse_w, params, xqqw, gbuf);
  k_argmax<<<2048, 256, 0, stream>>>(xqqw, xmaxf, xavg);
  k_bias2<<<32, 256, 0, stream>>>(convs1_w, xmaxf, xavg, params, bias2);
  k_gemm<<<1024, 256, 0, stream>>>(wbuf1, gbuf, params + 672, params + 1184, bias2, g1, 512, 128, 4);
  k_gemm<<<512, 256, 0, stream>>>(wbuf2, g1, params + 1696, params + 1952, nullptr, g2, 256, 512, 2);
  k_gemm3<<<512, 256, 0, stream>>>(g2, convs3_w, convs3_b, (float*)d_out);
}